// Round 12
// baseline (294.339 us; speedup 1.0000x reference)
//
#include <hip/hip_runtime.h>
#include <hip/hip_bf16.h>
#include <stdint.h>

#define BB   8
#define LSEQ 4096
#define HH   512
#define KIN  10
#define NC   64
#define CHK  64        // LSEQ / NC
#define KT   16        // k-tiles for compose stage 1
#define KC   (HH/KT)   // 32 k per tile
#define XPAD 12        // xc padded stride (48 B, 16B-aligned rows; 3 float4 per row)

// f32 output layout (elements): t_enc [0, 262144), h_fwd, h_bwd
#define OUT_TENC_N (BB*LSEQ*8)
#define HSIZE      ((size_t)BB*LSEQ*HH)

// ws layout (floats):
#define WOFF_WEFF 0
#define WOFF_BEFF 20480
#define WOFF_SG   22528
#define WOFF_SP   (WOFF_SG + 2*BB*NC*HH)          // +524288
#define WOFF_XC   (WOFF_SP + 2*BB*NC*HH)          // 1071104
#define WS_FLOATS (WOFF_XC + BB*LSEQ*XPAD)        // 1464320 floats = 5.86 MB
// compose partials (overlay inside SG/SP region, dead before scan<0> writes it):
#define POFF_W    WOFF_SG                          // [4*KT][KIN][HH]
#define POFF_B    (WOFF_SG + 4*KT*KIN*HH)

// ---------------- compose stage 1: per-(m, ktile) partial sums
__global__ __launch_bounds__(512)
void compose1(const float* __restrict__ fproj_w, const float* __restrict__ fproj_b,
              const float* __restrict__ bproj_w, const float* __restrict__ bproj_b,
              const float* __restrict__ f_wz, const float* __restrict__ f_wh,
              const float* __restrict__ b_wz, const float* __restrict__ b_wh,
              float* __restrict__ ws) {
    const int m  = blockIdx.x;       // 0=f_z 1=f_h 2=b_z 3=b_h
    const int kt = blockIdx.y;       // 0..KT-1
    const int j  = threadIdx.x;      // 0..511
    const float* P  = (m < 2) ? fproj_w : bproj_w;
    const float* pb = (m < 2) ? fproj_b : bproj_b;
    const float* W  = (m == 0) ? f_wz : (m == 1) ? f_wh : (m == 2) ? b_wz : b_wh;

    float acc[KIN];
    #pragma unroll
    for (int i = 0; i < KIN; i++) acc[i] = 0.f;
    float accb = 0.f;
    #pragma unroll 4
    for (int kk = 0; kk < KC; kk++) {
        const int k = kt * KC + kk;
        float w = W[(size_t)k*HH + j];            // coalesced
        accb = fmaf(pb[k], w, accb);              // uniform
        #pragma unroll
        for (int i = 0; i < KIN; i++) acc[i] = fmaf(P[(size_t)i*HH + k], w, acc[i]);
    }
    const int mt = m*KT + kt;
    #pragma unroll
    for (int i = 0; i < KIN; i++) ws[POFF_W + ((size_t)mt*KIN + i)*HH + j] = acc[i];
    ws[POFF_B + (size_t)mt*HH + j] = accb;
}

// ---------------- compose stage 2: reduce partials + bias
__global__ __launch_bounds__(512)
void compose2(const float* __restrict__ f_bz, const float* __restrict__ f_bh,
              const float* __restrict__ b_bz, const float* __restrict__ b_bh,
              float* __restrict__ ws) {
    const int m = blockIdx.x, j = threadIdx.x;
    const float* wb = (m == 0) ? f_bz : (m == 1) ? f_bh : (m == 2) ? b_bz : b_bh;
    #pragma unroll
    for (int i = 0; i < KIN; i++) {
        float s = 0.f;
        #pragma unroll
        for (int kt = 0; kt < KT; kt++)
            s += ws[POFF_W + ((size_t)(m*KT + kt)*KIN + i)*HH + j];
        ws[WOFF_WEFF + (m*KIN + i)*HH + j] = s;
    }
    float sb = wb[j];
    #pragma unroll
    for (int kt = 0; kt < KT; kt++) sb += ws[POFF_B + (size_t)(m*KT + kt)*HH + j];
    ws[WOFF_BEFF + m*HH + j] = sb;
}

// ---------------- xc + t_enc: one thread per timestep
__global__ __launch_bounds__(256)
void xc_kernel(const float* __restrict__ x, const float* __restrict__ t,
               const float* __restrict__ te_w1, const float* __restrict__ te_b1,
               const float* __restrict__ te_w2, const float* __restrict__ te_b2,
               float* __restrict__ ws, float* __restrict__ out) {
    const int idx = blockIdx.x * 256 + threadIdx.x;   // b*L + l
    const int b = idx >> 12;
    float ts = t[idx] - t[(size_t)b << 12];

    float h1[8];
    #pragma unroll
    for (int j = 0; j < 8; j++) h1[j] = fmaxf(0.f, fmaf(ts, te_w1[j], te_b1[j]));

    float o[8];
    #pragma unroll
    for (int j = 0; j < 8; j++) {
        float v = te_b2[j];
        #pragma unroll
        for (int k = 0; k < 8; k++) v = fmaf(h1[k], te_w2[k*8 + j], v);
        o[j] = v;
    }
    float4* ob = reinterpret_cast<float4*>(&out[(size_t)idx * 8]);
    ob[0] = make_float4(o[0], o[1], o[2], o[3]);
    ob[1] = make_float4(o[4], o[5], o[6], o[7]);
    float2 xv = reinterpret_cast<const float2*>(x)[idx];
    float4* xb = reinterpret_cast<float4*>(&ws[WOFF_XC + (size_t)idx * XPAD]);
    xb[0] = make_float4(xv.x, xv.y, o[0], o[1]);
    xb[1] = make_float4(o[2], o[3], o[4], o[5]);
    xb[2] = make_float4(o[6], o[7], 0.f, 0.f);
}

// ---------------- scan v4: both directions in ONE launch (grid z = d), all
// register indices compile-time static; runtime d handled by scalar selects.
template<int EMIT>
__global__ __launch_bounds__(512)
void scan4(const float* __restrict__ weff, const float* __restrict__ beff,
           const float* __restrict__ xc,
           float* __restrict__ sg, float* __restrict__ sp,
           float* __restrict__ out) {
    const int c = blockIdx.x;      // chunk (walk order)
    const int b = blockIdx.y;      // batch
    const int d = blockIdx.z;      // 0 fwd, 1 bwd (runtime, wave-uniform)
    const int h = threadIdx.x;     // 0..511
    const bool fwd = (d == 0);

    float wz[KIN], wh[KIN];
    #pragma unroll
    for (int i = 0; i < KIN; i++) {
        wz[i] = weff[((2*d    )*KIN + i)*HH + h];
        wh[i] = weff[((2*d + 1)*KIN + i)*HH + h];
    }
    const float bz = beff[(2*d    )*HH + h];
    const float bh = beff[(2*d + 1)*HH + h];

    const int t0 = fwd ? c * CHK : LSEQ - (c + 1) * CHK;   // chunk base (memory)
    const float4* __restrict__ q4 =
        reinterpret_cast<const float4*>(xc + ((size_t)b * LSEQ + t0) * XPAD);

    float Hacc = 0.f, Pr = 1.f;
    if (EMIT) {   // fold carries of earlier-in-walk chunks, 4-wide unrolled
        const float* g = sg + (size_t)((d*BB + b)*NC)*HH + h;
        const float* p = sp + (size_t)((d*BB + b)*NC)*HH + h;
        int cc = 0;
        for (; cc + 4 <= c; cc += 4) {   // 4 independent load pairs per batch
            float ga = g[(size_t)(cc+0)*HH], gb = g[(size_t)(cc+1)*HH];
            float gc = g[(size_t)(cc+2)*HH], gd = g[(size_t)(cc+3)*HH];
            float pa = p[(size_t)(cc+0)*HH], pb = p[(size_t)(cc+1)*HH];
            float pc = p[(size_t)(cc+2)*HH], pd = p[(size_t)(cc+3)*HH];
            Hacc = fmaf(Pr, ga, Hacc);  Pr *= pa;
            Hacc = fmaf(Pr, gb, Hacc);  Pr *= pb;
            Hacc = fmaf(Pr, gc, Hacc);  Pr *= pc;
            Hacc = fmaf(Pr, gd, Hacc);  Pr *= pd;
        }
        for (; cc < c; cc++) {
            Hacc = fmaf(Pr, g[(size_t)cc*HH], Hacc);
            Pr  *= p[(size_t)cc*HH];
        }
    }

    float* ob = out + OUT_TENC_N + (size_t)d * HSIZE + (size_t)b * LSEQ * HH + h;

    for (int s4 = 0; s4 < CHK; s4 += 4) {
        const int mb = fwd ? s4 : (CHK - 4 - s4);   // group base (memory rows)
        const float4* qq = q4 + (size_t)mb * 3;
        // 48 contiguous floats, uniform across block, into NAMED regs
        float4 v0 = qq[0],  v1 = qq[1],  v2 = qq[2],  v3 = qq[3];
        float4 v4 = qq[4],  v5 = qq[5],  v6 = qq[6],  v7 = qq[7];
        float4 v8 = qq[8],  v9 = qq[9],  v10 = qq[10], v11 = qq[11];

        float g0,g1,g2,g3, a0,a1,a2,a3;   // MEMORY-row order, named scalars
        #define MGRU_STEP(G, A, X, Y, Z)                                       \
        {                                                                      \
            float zp = bz, hp = bh;                                            \
            zp = fmaf(X.x, wz[0], zp);  hp = fmaf(X.x, wh[0], hp);             \
            zp = fmaf(X.y, wz[1], zp);  hp = fmaf(X.y, wh[1], hp);             \
            zp = fmaf(X.z, wz[2], zp);  hp = fmaf(X.z, wh[2], hp);             \
            zp = fmaf(X.w, wz[3], zp);  hp = fmaf(X.w, wh[3], hp);             \
            zp = fmaf(Y.x, wz[4], zp);  hp = fmaf(Y.x, wh[4], hp);             \
            zp = fmaf(Y.y, wz[5], zp);  hp = fmaf(Y.y, wh[5], hp);             \
            zp = fmaf(Y.z, wz[6], zp);  hp = fmaf(Y.z, wh[6], hp);             \
            zp = fmaf(Y.w, wz[7], zp);  hp = fmaf(Y.w, wh[7], hp);             \
            zp = fmaf(Z.x, wz[8], zp);  hp = fmaf(Z.x, wh[8], hp);             \
            zp = fmaf(Z.y, wz[9], zp);  hp = fmaf(Z.y, wh[9], hp);             \
            float z = __builtin_amdgcn_rcpf(1.f + __expf(-zp));                \
            G = z * hp;                                                        \
            A = 1.f - z;                                                       \
        }
        MGRU_STEP(g0, a0, v0, v1, v2)
        MGRU_STEP(g1, a1, v3, v4, v5)
        MGRU_STEP(g2, a2, v6, v7, v8)
        MGRU_STEP(g3, a3, v9, v10, v11)
        #undef MGRU_STEP

        // walk-order tail; runtime d -> scalar selects between named regs
        #define MGRU_TAIL(U, GF, AF, GB, AB)                                   \
        {                                                                      \
            const float gu = fwd ? GF : GB;                                    \
            const float au = fwd ? AF : AB;                                    \
            if (EMIT) {                                                        \
                const int trow = fwd ? (s4 + U) : (CHK - 1 - s4 - U);          \
                ob[(size_t)(t0 + trow) * HH] = Hacc;  /* pre-update = shift */ \
            }                                                                  \
            Hacc = fmaf(Pr, gu, Hacc);                                         \
            Pr *= au;                                                          \
        }
        MGRU_TAIL(0, g0, a0, g3, a3)
        MGRU_TAIL(1, g1, a1, g2, a2)
        MGRU_TAIL(2, g2, a2, g1, a1)
        MGRU_TAIL(3, g3, a3, g0, a0)
        #undef MGRU_TAIL
    }

    if (!EMIT) {
        sg[(size_t)((d*BB + b)*NC + c)*HH + h] = Hacc;
        sp[(size_t)((d*BB + b)*NC + c)*HH + h] = Pr;
    }
}

// ---------------- serial fallback (no ws) — safety net only
__global__ __launch_bounds__(256)
void scan_serial(const float* __restrict__ x, const float* __restrict__ t,
                 const float* __restrict__ te_w1, const float* __restrict__ te_b1,
                 const float* __restrict__ te_w2, const float* __restrict__ te_b2,
                 const float* __restrict__ PWf, const float* __restrict__ PBf,
                 const float* __restrict__ PWb, const float* __restrict__ PBb,
                 const float* __restrict__ f_wz, const float* __restrict__ f_bz,
                 const float* __restrict__ f_wh, const float* __restrict__ f_bh,
                 const float* __restrict__ b_wz, const float* __restrict__ b_bz,
                 const float* __restrict__ b_wh, const float* __restrict__ b_bh,
                 float* __restrict__ out) {
    const int hg = blockIdx.x, b = blockIdx.y, d = blockIdx.z;
    const int h = hg * 256 + threadIdx.x;
    const float* PW = d ? PWb : PWf;   const float* PB = d ? PBb : PBf;
    const float* WZ = d ? b_wz : f_wz; const float* BZ = d ? b_bz : f_bz;
    const float* WH = d ? b_wh : f_wh; const float* BH = d ? b_bh : f_bh;

    float wz[KIN], wh[KIN];
    #pragma unroll
    for (int i = 0; i < KIN; i++) { wz[i] = 0.f; wh[i] = 0.f; }
    float bz = BZ[h], bh = BH[h];
    for (int k = 0; k < HH; k++) {
        float vz = WZ[k*HH + h], vh = WH[k*HH + h], pbk = PB[k];
        bz = fmaf(pbk, vz, bz);  bh = fmaf(pbk, vh, bh);
        #pragma unroll
        for (int i = 0; i < KIN; i++) {
            wz[i] = fmaf(PW[i*HH + k], vz, wz[i]);
            wh[i] = fmaf(PW[i*HH + k], vh, wh[i]);
        }
    }
    __shared__ float w2s[64], w1s[8], b1s[8], b2s[8], xcs[256*KIN];
    if (threadIdx.x < 64) w2s[threadIdx.x] = te_w2[threadIdx.x];
    if (threadIdx.x < 8) {
        w1s[threadIdx.x] = te_w1[threadIdx.x];
        b1s[threadIdx.x] = te_b1[threadIdx.x];
        b2s[threadIdx.x] = te_b2[threadIdx.x];
    }
    const float t_b0 = t[(size_t)b * LSEQ];
    float Hacc = 0.f, Pr = 1.f;
    float* ob = out + OUT_TENC_N + (size_t)d*HSIZE + (size_t)b*LSEQ*HH + h;
    for (int cc = 0; cc < LSEQ/256; cc++) {
        const int t0 = (d == 0) ? cc*256 : LSEQ - (cc+1)*256;
        __syncthreads();
        {
            const size_t gi = (size_t)b*LSEQ + t0 + threadIdx.x;
            float ts = t[gi] - t_b0;
            float h1[8];
            #pragma unroll
            for (int j = 0; j < 8; j++) h1[j] = fmaxf(0.f, fmaf(ts, w1s[j], b1s[j]));
            float* xr = &xcs[threadIdx.x * KIN];
            float2 xv = reinterpret_cast<const float2*>(x)[gi];
            xr[0] = xv.x; xr[1] = xv.y;
            #pragma unroll
            for (int j = 0; j < 8; j++) {
                float v = b2s[j];
                #pragma unroll
                for (int k = 0; k < 8; k++) v = fmaf(h1[k], w2s[k*8+j], v);
                xr[2+j] = v;
            }
        }
        __syncthreads();
        for (int tt = 0; tt < 256; tt++) {
            const int row = (d == 0) ? tt : (255 - tt);
            const float* xr = &xcs[row * KIN];
            float zp = bz, hp = bh;
            #pragma unroll
            for (int i = 0; i < KIN; i++) { zp = fmaf(xr[i], wz[i], zp); hp = fmaf(xr[i], wh[i], hp); }
            float z = __builtin_amdgcn_rcpf(1.f + __expf(-zp));
            ob[(size_t)(t0 + row) * HH] = Hacc;
            Hacc = fmaf(Pr, z * hp, Hacc);
            Pr *= (1.f - z);
        }
    }
}

__global__ __launch_bounds__(256)
void tenc_fb(const float* __restrict__ t,
             const float* __restrict__ te_w1, const float* __restrict__ te_b1,
             const float* __restrict__ te_w2, const float* __restrict__ te_b2,
             float* __restrict__ out) {
    int idx = blockIdx.x * 256 + threadIdx.x;
    int b = idx >> 12;
    float ts = t[idx] - t[(size_t)b << 12];
    float h1[8];
    #pragma unroll
    for (int j = 0; j < 8; j++) h1[j] = fmaxf(0.f, fmaf(ts, te_w1[j], te_b1[j]));
    float o[8];
    #pragma unroll
    for (int j = 0; j < 8; j++) {
        float v = te_b2[j];
        #pragma unroll
        for (int k = 0; k < 8; k++) v = fmaf(h1[k], te_w2[k*8 + j], v);
        o[j] = v;
    }
    float4* ob = reinterpret_cast<float4*>(&out[(size_t)idx * 8]);
    ob[0] = make_float4(o[0], o[1], o[2], o[3]);
    ob[1] = make_float4(o[4], o[5], o[6], o[7]);
}

extern "C" void kernel_launch(void* const* d_in, const int* in_sizes, int n_in,
                              void* d_out, int out_size, void* d_ws, size_t ws_size,
                              hipStream_t stream) {
    const float* x       = (const float*)d_in[0];
    const float* t       = (const float*)d_in[1];
    const float* te_w1   = (const float*)d_in[2];
    const float* te_b1   = (const float*)d_in[3];
    const float* te_w2   = (const float*)d_in[4];
    const float* te_b2   = (const float*)d_in[5];
    const float* fproj_w = (const float*)d_in[6];
    const float* fproj_b = (const float*)d_in[7];
    const float* bproj_w = (const float*)d_in[8];
    const float* bproj_b = (const float*)d_in[9];
    const float* f_wz    = (const float*)d_in[10];
    const float* f_bz    = (const float*)d_in[11];
    const float* f_wh    = (const float*)d_in[12];
    const float* f_bh    = (const float*)d_in[13];
    const float* b_wz    = (const float*)d_in[14];
    const float* b_bz    = (const float*)d_in[15];
    const float* b_wh    = (const float*)d_in[16];
    const float* b_bh    = (const float*)d_in[17];
    float* out           = (float*)d_out;     // outputs are float32
    float* ws            = (float*)d_ws;

    if (ws_size >= (size_t)WS_FLOATS * sizeof(float)) {
        xc_kernel<<<(BB*LSEQ)/256, 256, 0, stream>>>(x, t, te_w1, te_b1, te_w2, te_b2, ws, out);
        dim3 gc(4, KT);
        compose1<<<gc, 512, 0, stream>>>(fproj_w, fproj_b, bproj_w, bproj_b,
                                         f_wz, f_wh, b_wz, b_wh, ws);
        compose2<<<4, 512, 0, stream>>>(f_bz, f_bh, b_bz, b_bh, ws);

        dim3 g(NC, BB, 2);
        // PROBE: scan4<0> is idempotent — run 3x. (dur - expected_base)/2 = cost(pass0).
        scan4<0><<<g, 512, 0, stream>>>(ws + WOFF_WEFF, ws + WOFF_BEFF, ws + WOFF_XC,
                                        ws + WOFF_SG, ws + WOFF_SP, out);
        scan4<0><<<g, 512, 0, stream>>>(ws + WOFF_WEFF, ws + WOFF_BEFF, ws + WOFF_XC,
                                        ws + WOFF_SG, ws + WOFF_SP, out);
        scan4<0><<<g, 512, 0, stream>>>(ws + WOFF_WEFF, ws + WOFF_BEFF, ws + WOFF_XC,
                                        ws + WOFF_SG, ws + WOFF_SP, out);
        scan4<1><<<g, 512, 0, stream>>>(ws + WOFF_WEFF, ws + WOFF_BEFF, ws + WOFF_XC,
                                        ws + WOFF_SG, ws + WOFF_SP, out);
    } else {
        tenc_fb<<<(BB*LSEQ)/256, 256, 0, stream>>>(t, te_w1, te_b1, te_w2, te_b2, out);
        dim3 g(2, BB, 2);
        scan_serial<<<g, 256, 0, stream>>>(x, t, te_w1, te_b1, te_w2, te_b2,
                                           fproj_w, fproj_b, bproj_w, bproj_b,
                                           f_wz, f_bz, f_wh, f_bh,
                                           b_wz, b_bz, b_wh, b_bh, out);
    }
}

// Round 14
// 234.001 us; speedup vs baseline: 1.2579x; 1.2579x over previous
//
#include <hip/hip_runtime.h>
#include <hip/hip_bf16.h>
#include <stdint.h>

#define BB   8
#define LSEQ 4096
#define HH   512
#define KIN  10
#define NC   64
#define CHK  64        // LSEQ / NC
#define KT   16        // k-tiles for compose stage 1
#define KC   (HH/KT)   // 32 k per tile
#define XPAD 12        // xc padded stride (48 B, 16B-aligned rows; 3 float4 per row)

// f32 output layout (elements): t_enc [0, 262144), h_fwd, h_bwd
#define OUT_TENC_N (BB*LSEQ*8)
#define HSIZE      ((size_t)BB*LSEQ*HH)

// ws layout (floats):
#define WOFF_WEFF 0
#define WOFF_BEFF 20480
#define WOFF_SG   22528
#define WOFF_SP   (WOFF_SG + 2*BB*NC*HH)          // +524288
#define WOFF_XC   (WOFF_SP + 2*BB*NC*HH)          // 1071104
#define WS_FLOATS (WOFF_XC + BB*LSEQ*XPAD)        // 1464320 floats = 5.86 MB
// compose partials (overlay inside SG/SP region, dead before scan passes write it):
#define POFF_W    WOFF_SG                          // [4*KT][KIN][HH]
#define POFF_B    (WOFF_SG + 4*KT*KIN*HH)

// ---------------- compose stage 1: per-(m, ktile) partial sums
__global__ __launch_bounds__(512)
void compose1(const float* __restrict__ fproj_w, const float* __restrict__ fproj_b,
              const float* __restrict__ bproj_w, const float* __restrict__ bproj_b,
              const float* __restrict__ f_wz, const float* __restrict__ f_wh,
              const float* __restrict__ b_wz, const float* __restrict__ b_wh,
              float* __restrict__ ws) {
    const int m  = blockIdx.x;       // 0=f_z 1=f_h 2=b_z 3=b_h
    const int kt = blockIdx.y;       // 0..KT-1
    const int j  = threadIdx.x;      // 0..511
    const float* P  = (m < 2) ? fproj_w : bproj_w;
    const float* pb = (m < 2) ? fproj_b : bproj_b;
    const float* W  = (m == 0) ? f_wz : (m == 1) ? f_wh : (m == 2) ? b_wz : b_wh;

    float acc[KIN];
    #pragma unroll
    for (int i = 0; i < KIN; i++) acc[i] = 0.f;
    float accb = 0.f;
    #pragma unroll 4
    for (int kk = 0; kk < KC; kk++) {
        const int k = kt * KC + kk;
        float w = W[(size_t)k*HH + j];            // coalesced
        accb = fmaf(pb[k], w, accb);              // uniform
        #pragma unroll
        for (int i = 0; i < KIN; i++) acc[i] = fmaf(P[(size_t)i*HH + k], w, acc[i]);
    }
    const int mt = m*KT + kt;
    #pragma unroll
    for (int i = 0; i < KIN; i++) ws[POFF_W + ((size_t)mt*KIN + i)*HH + j] = acc[i];
    ws[POFF_B + (size_t)mt*HH + j] = accb;
}

// ---------------- compose stage 2: reduce partials + bias
__global__ __launch_bounds__(512)
void compose2(const float* __restrict__ f_bz, const float* __restrict__ f_bh,
              const float* __restrict__ b_bz, const float* __restrict__ b_bh,
              float* __restrict__ ws) {
    const int m = blockIdx.x, j = threadIdx.x;
    const float* wb = (m == 0) ? f_bz : (m == 1) ? f_bh : (m == 2) ? b_bz : b_bh;
    #pragma unroll
    for (int i = 0; i < KIN; i++) {
        float s = 0.f;
        #pragma unroll
        for (int kt = 0; kt < KT; kt++)
            s += ws[POFF_W + ((size_t)(m*KT + kt)*KIN + i)*HH + j];
        ws[WOFF_WEFF + (m*KIN + i)*HH + j] = s;
    }
    float sb = wb[j];
    #pragma unroll
    for (int kt = 0; kt < KT; kt++) sb += ws[POFF_B + (size_t)(m*KT + kt)*HH + j];
    ws[WOFF_BEFF + m*HH + j] = sb;
}

// ---------------- xc + t_enc: one thread per timestep
__global__ __launch_bounds__(256)
void xc_kernel(const float* __restrict__ x, const float* __restrict__ t,
               const float* __restrict__ te_w1, const float* __restrict__ te_b1,
               const float* __restrict__ te_w2, const float* __restrict__ te_b2,
               float* __restrict__ ws, float* __restrict__ out) {
    const int idx = blockIdx.x * 256 + threadIdx.x;   // b*L + l
    const int b = idx >> 12;
    float ts = t[idx] - t[(size_t)b << 12];

    float h1[8];
    #pragma unroll
    for (int j = 0; j < 8; j++) h1[j] = fmaxf(0.f, fmaf(ts, te_w1[j], te_b1[j]));

    float o[8];
    #pragma unroll
    for (int j = 0; j < 8; j++) {
        float v = te_b2[j];
        #pragma unroll
        for (int k = 0; k < 8; k++) v = fmaf(h1[k], te_w2[k*8 + j], v);
        o[j] = v;
    }
    float4* ob = reinterpret_cast<float4*>(&out[(size_t)idx * 8]);
    ob[0] = make_float4(o[0], o[1], o[2], o[3]);
    ob[1] = make_float4(o[4], o[5], o[6], o[7]);
    float2 xv = reinterpret_cast<const float2*>(x)[idx];
    float4* xb = reinterpret_cast<float4*>(&ws[WOFF_XC + (size_t)idx * XPAD]);
    xb[0] = make_float4(xv.x, xv.y, o[0], o[1]);
    xb[1] = make_float4(o[2], o[3], o[4], o[5]);
    xb[2] = make_float4(o[6], o[7], 0.f, 0.f);
}

// ---------------- pass0: per-chunk (G,P) summaries; 1 h/thread, 512 threads
__global__ __launch_bounds__(512)
void scan_sum(const float* __restrict__ weff, const float* __restrict__ beff,
              const float* __restrict__ xc,
              float* __restrict__ sg, float* __restrict__ sp) {
    const int c = blockIdx.x;      // chunk (walk order)
    const int b = blockIdx.y;      // batch
    const int d = blockIdx.z;      // 0 fwd, 1 bwd
    const int h = threadIdx.x;     // 0..511
    const bool fwd = (d == 0);

    float wz[KIN], wh[KIN];
    #pragma unroll
    for (int i = 0; i < KIN; i++) {
        wz[i] = weff[((2*d    )*KIN + i)*HH + h];
        wh[i] = weff[((2*d + 1)*KIN + i)*HH + h];
    }
    const float bz = beff[(2*d    )*HH + h];
    const float bh = beff[(2*d + 1)*HH + h];

    const int t0 = fwd ? c * CHK : LSEQ - (c + 1) * CHK;   // chunk base (memory)
    const float4* __restrict__ q4 =
        reinterpret_cast<const float4*>(xc + ((size_t)b * LSEQ + t0) * XPAD);

    float Hacc = 0.f, Pr = 1.f;

    for (int s4 = 0; s4 < CHK; s4 += 4) {
        const int mb = fwd ? s4 : (CHK - 4 - s4);   // group base (memory rows)
        const float4* qq = q4 + (size_t)mb * 3;
        float4 v0 = qq[0],  v1 = qq[1],  v2 = qq[2],  v3 = qq[3];
        float4 v4 = qq[4],  v5 = qq[5],  v6 = qq[6],  v7 = qq[7];
        float4 v8 = qq[8],  v9 = qq[9],  v10 = qq[10], v11 = qq[11];

        float g0,g1,g2,g3, a0,a1,a2,a3;   // MEMORY-row order, named scalars
        #define MGRU_STEP(G, A, X, Y, Z)                                       \
        {                                                                      \
            float zp = bz, hp = bh;                                            \
            zp = fmaf(X.x, wz[0], zp);  hp = fmaf(X.x, wh[0], hp);             \
            zp = fmaf(X.y, wz[1], zp);  hp = fmaf(X.y, wh[1], hp);             \
            zp = fmaf(X.z, wz[2], zp);  hp = fmaf(X.z, wh[2], hp);             \
            zp = fmaf(X.w, wz[3], zp);  hp = fmaf(X.w, wh[3], hp);             \
            zp = fmaf(Y.x, wz[4], zp);  hp = fmaf(Y.x, wh[4], hp);             \
            zp = fmaf(Y.y, wz[5], zp);  hp = fmaf(Y.y, wh[5], hp);             \
            zp = fmaf(Y.z, wz[6], zp);  hp = fmaf(Y.z, wh[6], hp);             \
            zp = fmaf(Y.w, wz[7], zp);  hp = fmaf(Y.w, wh[7], hp);             \
            zp = fmaf(Z.x, wz[8], zp);  hp = fmaf(Z.x, wh[8], hp);             \
            zp = fmaf(Z.y, wz[9], zp);  hp = fmaf(Z.y, wh[9], hp);             \
            float z = __builtin_amdgcn_rcpf(1.f + __expf(-zp));                \
            G = z * hp;                                                        \
            A = 1.f - z;                                                       \
        }
        MGRU_STEP(g0, a0, v0, v1, v2)
        MGRU_STEP(g1, a1, v3, v4, v5)
        MGRU_STEP(g2, a2, v6, v7, v8)
        MGRU_STEP(g3, a3, v9, v10, v11)
        #undef MGRU_STEP

        #define MGRU_TAIL(GF, AF, GB, AB)                                      \
        {                                                                      \
            const float gu = fwd ? GF : GB;                                    \
            const float au = fwd ? AF : AB;                                    \
            Hacc = fmaf(Pr, gu, Hacc);                                         \
            Pr *= au;                                                          \
        }
        MGRU_TAIL(g0, a0, g3, a3)
        MGRU_TAIL(g1, a1, g2, a2)
        MGRU_TAIL(g2, a2, g1, a1)
        MGRU_TAIL(g3, a3, g0, a0)
        #undef MGRU_TAIL
    }

    sg[(size_t)((d*BB + b)*NC + c)*HH + h] = Hacc;
    sp[(size_t)((d*BB + b)*NC + c)*HH + h] = Pr;
}

// ---------------- mid: in-place exclusive prefix over the NC chunk summaries
__global__ __launch_bounds__(512)
void midscan(float* __restrict__ sg, float* __restrict__ sp) {
    const int b = blockIdx.x;      // batch
    const int d = blockIdx.y;      // dir
    const int h = threadIdx.x;     // 0..511
    float* g = sg + (size_t)((d*BB + b)*NC)*HH + h;
    float* p = sp + (size_t)((d*BB + b)*NC)*HH + h;

    float accG = 0.f, accP = 1.f;
    for (int cc = 0; cc < NC; cc += 8) {
        float tg0 = g[(size_t)(cc+0)*HH], tg1 = g[(size_t)(cc+1)*HH];
        float tg2 = g[(size_t)(cc+2)*HH], tg3 = g[(size_t)(cc+3)*HH];
        float tg4 = g[(size_t)(cc+4)*HH], tg5 = g[(size_t)(cc+5)*HH];
        float tg6 = g[(size_t)(cc+6)*HH], tg7 = g[(size_t)(cc+7)*HH];
        float tp0 = p[(size_t)(cc+0)*HH], tp1 = p[(size_t)(cc+1)*HH];
        float tp2 = p[(size_t)(cc+2)*HH], tp3 = p[(size_t)(cc+3)*HH];
        float tp4 = p[(size_t)(cc+4)*HH], tp5 = p[(size_t)(cc+5)*HH];
        float tp6 = p[(size_t)(cc+6)*HH], tp7 = p[(size_t)(cc+7)*HH];
        #define MID1(K, TG, TP)                                                \
        {                                                                      \
            g[(size_t)(cc+K)*HH] = accG;                                       \
            p[(size_t)(cc+K)*HH] = accP;                                       \
            accG = fmaf(accP, TG, accG);                                       \
            accP *= TP;                                                        \
        }
        MID1(0, tg0, tp0) MID1(1, tg1, tp1) MID1(2, tg2, tp2) MID1(3, tg3, tp3)
        MID1(4, tg4, tp4) MID1(5, tg5, tp5) MID1(6, tg6, tp6) MID1(7, tg7, tp7)
        #undef MID1
    }
}

// ---------------- pass1: 2 h/thread, float2 loads/stores, direct carry read
__global__ __launch_bounds__(256)
void scan_emit(const float* __restrict__ weff, const float* __restrict__ beff,
               const float* __restrict__ xc,
               const float* __restrict__ sg, const float* __restrict__ sp,
               float* __restrict__ out) {
    const int c = blockIdx.x;      // chunk (walk order)
    const int b = blockIdx.y;      // batch
    const int d = blockIdx.z;      // 0 fwd, 1 bwd
    const int h2 = threadIdx.x;    // handles h = 2*h2, 2*h2+1
    const bool fwd = (d == 0);

    float2 wz[KIN], wh[KIN];
    #pragma unroll
    for (int i = 0; i < KIN; i++) {
        wz[i] = *reinterpret_cast<const float2*>(&weff[((2*d    )*KIN + i)*HH + 2*h2]);
        wh[i] = *reinterpret_cast<const float2*>(&weff[((2*d + 1)*KIN + i)*HH + 2*h2]);
    }
    const float2 bz2 = *reinterpret_cast<const float2*>(&beff[(2*d    )*HH + 2*h2]);
    const float2 bh2 = *reinterpret_cast<const float2*>(&beff[(2*d + 1)*HH + 2*h2]);

    const int t0 = fwd ? c * CHK : LSEQ - (c + 1) * CHK;   // chunk base (memory)
    const float4* __restrict__ q4 =
        reinterpret_cast<const float4*>(xc + ((size_t)b * LSEQ + t0) * XPAD);

    // exclusive-prefix carry (computed by midscan): one 8B load each
    float2 Hacc = *reinterpret_cast<const float2*>(
        &sg[(size_t)((d*BB + b)*NC + c)*HH + 2*h2]);
    float2 Pr   = *reinterpret_cast<const float2*>(
        &sp[(size_t)((d*BB + b)*NC + c)*HH + 2*h2]);

    float2* ob = reinterpret_cast<float2*>(
        out + OUT_TENC_N + (size_t)d * HSIZE + (size_t)b * LSEQ * HH + 2*h2);

    for (int s4 = 0; s4 < CHK; s4 += 4) {
        const int mb = fwd ? s4 : (CHK - 4 - s4);   // group base (memory rows)
        const float4* qq = q4 + (size_t)mb * 3;
        float4 v0 = qq[0],  v1 = qq[1],  v2 = qq[2],  v3 = qq[3];
        float4 v4 = qq[4],  v5 = qq[5],  v6 = qq[6],  v7 = qq[7];
        float4 v8 = qq[8],  v9 = qq[9],  v10 = qq[10], v11 = qq[11];

        float2 g0,g1,g2,g3, a0,a1,a2,a3;
        #define MGRU_STEP2(G, A, X, Y, Z)                                      \
        {                                                                      \
            float zx = bz2.x, zy = bz2.y, hx = bh2.x, hy = bh2.y;              \
            zx = fmaf(X.x, wz[0].x, zx);  zy = fmaf(X.x, wz[0].y, zy);         \
            hx = fmaf(X.x, wh[0].x, hx);  hy = fmaf(X.x, wh[0].y, hy);         \
            zx = fmaf(X.y, wz[1].x, zx);  zy = fmaf(X.y, wz[1].y, zy);         \
            hx = fmaf(X.y, wh[1].x, hx);  hy = fmaf(X.y, wh[1].y, hy);         \
            zx = fmaf(X.z, wz[2].x, zx);  zy = fmaf(X.z, wz[2].y, zy);         \
            hx = fmaf(X.z, wh[2].x, hx);  hy = fmaf(X.z, wh[2].y, hy);         \
            zx = fmaf(X.w, wz[3].x, zx);  zy = fmaf(X.w, wz[3].y, zy);         \
            hx = fmaf(X.w, wh[3].x, hx);  hy = fmaf(X.w, wh[3].y, hy);         \
            zx = fmaf(Y.x, wz[4].x, zx);  zy = fmaf(Y.x, wz[4].y, zy);         \
            hx = fmaf(Y.x, wh[4].x, hx);  hy = fmaf(Y.x, wh[4].y, hy);         \
            zx = fmaf(Y.y, wz[5].x, zx);  zy = fmaf(Y.y, wz[5].y, zy);         \
            hx = fmaf(Y.y, wh[5].x, hx);  hy = fmaf(Y.y, wh[5].y, hy);         \
            zx = fmaf(Y.z, wz[6].x, zx);  zy = fmaf(Y.z, wz[6].y, zy);         \
            hx = fmaf(Y.z, wh[6].x, hx);  hy = fmaf(Y.z, wh[6].y, hy);         \
            zx = fmaf(Y.w, wz[7].x, zx);  zy = fmaf(Y.w, wz[7].y, zy);         \
            hx = fmaf(Y.w, wh[7].x, hx);  hy = fmaf(Y.w, wh[7].y, hy);         \
            zx = fmaf(Z.x, wz[8].x, zx);  zy = fmaf(Z.x, wz[8].y, zy);         \
            hx = fmaf(Z.x, wh[8].x, hx);  hy = fmaf(Z.x, wh[8].y, hy);         \
            zx = fmaf(Z.y, wz[9].x, zx);  zy = fmaf(Z.y, wz[9].y, zy);         \
            hx = fmaf(Z.y, wh[9].x, hx);  hy = fmaf(Z.y, wh[9].y, hy);         \
            float sx = __builtin_amdgcn_rcpf(1.f + __expf(-zx));               \
            float sy = __builtin_amdgcn_rcpf(1.f + __expf(-zy));               \
            G = make_float2(sx * hx, sy * hy);                                 \
            A = make_float2(1.f - sx, 1.f - sy);                               \
        }
        MGRU_STEP2(g0, a0, v0, v1, v2)
        MGRU_STEP2(g1, a1, v3, v4, v5)
        MGRU_STEP2(g2, a2, v6, v7, v8)
        MGRU_STEP2(g3, a3, v9, v10, v11)
        #undef MGRU_STEP2

        #define MGRU_TAIL2(U, GF, AF, GB, AB)                                  \
        {                                                                      \
            const float2 gu = fwd ? GF : GB;                                   \
            const float2 au = fwd ? AF : AB;                                   \
            const int trow = fwd ? (s4 + U) : (CHK - 1 - s4 - U);              \
            ob[(size_t)(t0 + trow) * (HH/2)] = Hacc;  /* pre-update = shift */ \
            Hacc.x = fmaf(Pr.x, gu.x, Hacc.x);                                 \
            Hacc.y = fmaf(Pr.y, gu.y, Hacc.y);                                 \
            Pr.x *= au.x;                                                      \
            Pr.y *= au.y;                                                      \
        }
        MGRU_TAIL2(0, g0, a0, g3, a3)
        MGRU_TAIL2(1, g1, a1, g2, a2)
        MGRU_TAIL2(2, g2, a2, g1, a1)
        MGRU_TAIL2(3, g3, a3, g0, a0)
        #undef MGRU_TAIL2
    }
}

// ---------------- serial fallback (no ws) — safety net only
__global__ __launch_bounds__(256)
void scan_serial(const float* __restrict__ x, const float* __restrict__ t,
                 const float* __restrict__ te_w1, const float* __restrict__ te_b1,
                 const float* __restrict__ te_w2, const float* __restrict__ te_b2,
                 const float* __restrict__ PWf, const float* __restrict__ PBf,
                 const float* __restrict__ PWb, const float* __restrict__ PBb,
                 const float* __restrict__ f_wz, const float* __restrict__ f_bz,
                 const float* __restrict__ f_wh, const float* __restrict__ f_bh,
                 const float* __restrict__ b_wz, const float* __restrict__ b_bz,
                 const float* __restrict__ b_wh, const float* __restrict__ b_bh,
                 float* __restrict__ out) {
    const int hg = blockIdx.x, b = blockIdx.y, d = blockIdx.z;
    const int h = hg * 256 + threadIdx.x;
    const float* PW = d ? PWb : PWf;   const float* PB = d ? PBb : PBf;
    const float* WZ = d ? b_wz : f_wz; const float* BZ = d ? b_bz : f_bz;
    const float* WH = d ? b_wh : f_wh; const float* BH = d ? b_bh : f_bh;

    float wz[KIN], wh[KIN];
    #pragma unroll
    for (int i = 0; i < KIN; i++) { wz[i] = 0.f; wh[i] = 0.f; }
    float bz = BZ[h], bh = BH[h];
    for (int k = 0; k < HH; k++) {
        float vz = WZ[k*HH + h], vh = WH[k*HH + h], pbk = PB[k];
        bz = fmaf(pbk, vz, bz);  bh = fmaf(pbk, vh, bh);
        #pragma unroll
        for (int i = 0; i < KIN; i++) {
            wz[i] = fmaf(PW[i*HH + k], vz, wz[i]);
            wh[i] = fmaf(PW[i*HH + k], vh, wh[i]);
        }
    }
    __shared__ float w2s[64], w1s[8], b1s[8], b2s[8], xcs[256*KIN];
    if (threadIdx.x < 64) w2s[threadIdx.x] = te_w2[threadIdx.x];
    if (threadIdx.x < 8) {
        w1s[threadIdx.x] = te_w1[threadIdx.x];
        b1s[threadIdx.x] = te_b1[threadIdx.x];
        b2s[threadIdx.x] = te_b2[threadIdx.x];
    }
    const float t_b0 = t[(size_t)b * LSEQ];
    float Hacc = 0.f, Pr = 1.f;
    float* ob = out + OUT_TENC_N + (size_t)d*HSIZE + (size_t)b*LSEQ*HH + h;
    for (int cc = 0; cc < LSEQ/256; cc++) {
        const int t0 = (d == 0) ? cc*256 : LSEQ - (cc+1)*256;
        __syncthreads();
        {
            const size_t gi = (size_t)b*LSEQ + t0 + threadIdx.x;
            float ts = t[gi] - t_b0;
            float h1[8];
            #pragma unroll
            for (int j = 0; j < 8; j++) h1[j] = fmaxf(0.f, fmaf(ts, w1s[j], b1s[j]));
            float* xr = &xcs[threadIdx.x * KIN];
            float2 xv = reinterpret_cast<const float2*>(x)[gi];
            xr[0] = xv.x; xr[1] = xv.y;
            #pragma unroll
            for (int j = 0; j < 8; j++) {
                float v = b2s[j];
                #pragma unroll
                for (int k = 0; k < 8; k++) v = fmaf(h1[k], w2s[k*8+j], v);
                xr[2+j] = v;
            }
        }
        __syncthreads();
        for (int tt = 0; tt < 256; tt++) {
            const int row = (d == 0) ? tt : (255 - tt);
            const float* xr = &xcs[row * KIN];
            float zp = bz, hp = bh;
            #pragma unroll
            for (int i = 0; i < KIN; i++) { zp = fmaf(xr[i], wz[i], zp); hp = fmaf(xr[i], wh[i], hp); }
            float z = __builtin_amdgcn_rcpf(1.f + __expf(-zp));
            ob[(size_t)(t0 + row) * HH] = Hacc;
            Hacc = fmaf(Pr, z * hp, Hacc);
            Pr *= (1.f - z);
        }
    }
}

__global__ __launch_bounds__(256)
void tenc_fb(const float* __restrict__ t,
             const float* __restrict__ te_w1, const float* __restrict__ te_b1,
             const float* __restrict__ te_w2, const float* __restrict__ te_b2,
             float* __restrict__ out) {
    int idx = blockIdx.x * 256 + threadIdx.x;
    int b = idx >> 12;
    float ts = t[idx] - t[(size_t)b << 12];
    float h1[8];
    #pragma unroll
    for (int j = 0; j < 8; j++) h1[j] = fmaxf(0.f, fmaf(ts, te_w1[j], te_b1[j]));
    float o[8];
    #pragma unroll
    for (int j = 0; j < 8; j++) {
        float v = te_b2[j];
        #pragma unroll
        for (int k = 0; k < 8; k++) v = fmaf(h1[k], te_w2[k*8 + j], v);
        o[j] = v;
    }
    float4* ob = reinterpret_cast<float4*>(&out[(size_t)idx * 8]);
    ob[0] = make_float4(o[0], o[1], o[2], o[3]);
    ob[1] = make_float4(o[4], o[5], o[6], o[7]);
}

extern "C" void kernel_launch(void* const* d_in, const int* in_sizes, int n_in,
                              void* d_out, int out_size, void* d_ws, size_t ws_size,
                              hipStream_t stream) {
    const float* x       = (const float*)d_in[0];
    const float* t       = (const float*)d_in[1];
    const float* te_w1   = (const float*)d_in[2];
    const float* te_b1   = (const float*)d_in[3];
    const float* te_w2   = (const float*)d_in[4];
    const float* te_b2   = (const float*)d_in[5];
    const float* fproj_w = (const float*)d_in[6];
    const float* fproj_b = (const float*)d_in[7];
    const float* bproj_w = (const float*)d_in[8];
    const float* bproj_b = (const float*)d_in[9];
    const float* f_wz    = (const float*)d_in[10];
    const float* f_bz    = (const float*)d_in[11];
    const float* f_wh    = (const float*)d_in[12];
    const float* f_bh    = (const float*)d_in[13];
    const float* b_wz    = (const float*)d_in[14];
    const float* b_bz    = (const float*)d_in[15];
    const float* b_wh    = (const float*)d_in[16];
    const float* b_bh    = (const float*)d_in[17];
    float* out           = (float*)d_out;     // outputs are float32
    float* ws            = (float*)d_ws;

    if (ws_size >= (size_t)WS_FLOATS * sizeof(float)) {
        xc_kernel<<<(BB*LSEQ)/256, 256, 0, stream>>>(x, t, te_w1, te_b1, te_w2, te_b2, ws, out);
        dim3 gc(4, KT);
        compose1<<<gc, 512, 0, stream>>>(fproj_w, fproj_b, bproj_w, bproj_b,
                                         f_wz, f_wh, b_wz, b_wh, ws);
        compose2<<<4, 512, 0, stream>>>(f_bz, f_bh, b_bz, b_bh, ws);

        dim3 g(NC, BB, 2);
        scan_sum<<<g, 512, 0, stream>>>(ws + WOFF_WEFF, ws + WOFF_BEFF, ws + WOFF_XC,
                                        ws + WOFF_SG, ws + WOFF_SP);
        dim3 gm(BB, 2);
        midscan<<<gm, 512, 0, stream>>>(ws + WOFF_SG, ws + WOFF_SP);
        scan_emit<<<g, 256, 0, stream>>>(ws + WOFF_WEFF, ws + WOFF_BEFF, ws + WOFF_XC,
                                         ws + WOFF_SG, ws + WOFF_SP, out);
    } else {
        tenc_fb<<<(BB*LSEQ)/256, 256, 0, stream>>>(t, te_w1, te_b1, te_w2, te_b2, out);
        dim3 gs(2, BB, 2);
        scan_serial<<<gs, 256, 0, stream>>>(x, t, te_w1, te_b1, te_w2, te_b2,
                                            fproj_w, fproj_b, bproj_w, bproj_b,
                                            f_wz, f_bz, f_wh, f_bh,
                                            b_wz, b_bz, b_wh, b_bh, out);
    }
}